// Round 1
// 330.800 us; speedup vs baseline: 1.1370x; 1.1370x over previous
//
#include <hip/hip_runtime.h>
#include <cmath>

// ---------------------------------------------------------------------------
// Problem constants (B=8, H=W=64, C=192, 3 dilation branches of d=64, heads=64)
// ---------------------------------------------------------------------------
#define kB    8
#define kH    64
#define kW    64
#define kHW   4096          // H*W
#define kC    192
#define kD    64            // channels per dilation branch == head_dim
#define kM    (kB * kHW)    // 32768 total pixels
#define kNQKV 576           // 3*C

typedef unsigned short ushort_t;
typedef __attribute__((ext_vector_type(8))) short  s8v;   // 8 bf16 (4 VGPRs)
typedef __attribute__((ext_vector_type(4))) float  f4v;   // MFMA C/D frag

__device__ inline unsigned short bf16r(float f) {   // round-to-nearest-even
    union { float f; unsigned u; } v; v.f = f;
    unsigned u = v.u + 0x7FFFu + ((v.u >> 16) & 1u);
    return (unsigned short)(u >> 16);
}
__device__ inline float bfu(short s) {              // bf16 -> fp32
    union { unsigned u; float f; } v;
    v.u = ((unsigned)(unsigned short)s) << 16;
    return v.f;
}

// ---------------------------------------------------------------------------
// fp32 -> bf16 pairwise converter
// ---------------------------------------------------------------------------
__global__ void cvt_bf16(const float* __restrict__ src, unsigned* __restrict__ dst, int n2) {
    int i = blockIdx.x * 256 + threadIdx.x;
    if (i >= n2) return;
    float2 f = ((const float2*)src)[i];
    dst[i] = (unsigned)bf16r(f.x) | ((unsigned)bf16r(f.y) << 16);
}

// ---------------------------------------------------------------------------
// deform weights: dw (o,c,kk) fp32 -> dwtb[kk][o][c] bf16
// ---------------------------------------------------------------------------
__global__ void dw_tb(const float* __restrict__ dw, ushort_t* __restrict__ dwtb) {
    int l = blockIdx.x * 256 + threadIdx.x;   // 64*64*9 = 36864
    if (l >= kD * kD * 9) return;
    int o = l / 576;
    int c = (l / 9) % 64;
    int kk = l % 9;
    dwtb[(kk * 64 + o) * 64 + c] = bf16r(dw[l]);
}

// ---------------------------------------------------------------------------
// offset-conv weights: ow (18,64,3,3) fp32 -> owtb[kk][n=32 pad][c=64] bf16
// ---------------------------------------------------------------------------
__global__ void ow_tb(const float* __restrict__ ow, ushort_t* __restrict__ owtb) {
    int l = blockIdx.x * 256 + threadIdx.x;   // 9*32*64 = 18432
    if (l >= 9 * 32 * 64) return;
    int kk = l >> 11;
    int j  = (l >> 6) & 31;
    int c  = l & 63;
    owtb[l] = (j < 18) ? bf16r(ow[j * 576 + c * 9 + kk]) : (ushort_t)0;
}

// ---------------------------------------------------------------------------
// QKV weight pack: W fp32 [n=576][c=192] -> awb[strip s=36][kc=6][lane=64][8]
// A-fragment order for mfma_f32_16x16x32_bf16:
//   awb[s][kc][lane][j] = W[s*16 + (lane&15)][kc*32 + (lane>>4)*8 + j]
// One wave A-load becomes a single lane-linear 1 KB coalesced read.
// ---------------------------------------------------------------------------
__global__ void qw_pack(const float* __restrict__ w, ushort_t* __restrict__ awb) {
    int idx = blockIdx.x * 256 + threadIdx.x;   // 36*6*64 = 13824
    if (idx >= 36 * 6 * 64) return;
    int lane = idx & 63;
    int kc   = (idx >> 6) % 6;
    int s    = idx / 384;
    int row  = s * 16 + (lane & 15);
    int k0   = kc * 32 + (lane >> 4) * 8;
    const float* src = w + (size_t)row * kC + k0;
    ushort_t* dst = awb + (size_t)idx * 8;
#pragma unroll
    for (int j = 0; j < 8; ++j) dst[j] = bf16r(src[j]);
}

// ---------------------------------------------------------------------------
// Kernel 1 (round-11 rewrite): QKV projection GEMM, LDS-staged.
// Old version was latency-bound (MfmaUtil 3.8%, VALUBusy 4.7%, 68 us):
// every operand was a 16-line scattered global gather, x strip re-read 36x.
// Now:
//  - block = 64 pixels x 192 output channels (3 tensors), grid (512, 3)
//  - x strip staged once in LDS via coalesced uint4 loads, XOR-swizzled
//    (byte ^= (row&7)<<4) so ds_read_b128 B-frags are bank-balanced
//  - A-frags from qw_pack'd weights: one lane-linear 1 KB load per frag
//  - 72 MFMAs/wave on one staging pass; 24.6 KB LDS -> 6 blocks/CU
// Output identical layout: 9 bf16 pixel-major tensors [ty][p][64].
// ---------------------------------------------------------------------------
__global__ __launch_bounds__(256) void qkv_mfma3(const ushort_t* __restrict__ xb,
                                                 const ushort_t* __restrict__ awb,
                                                 ushort_t* __restrict__ qkvpx) {
    __shared__ ushort_t xs[64 * kC];            // 24576 B, swizzled rows of 384 B

    const int tid = threadIdx.x;
    const int bx  = blockIdx.x;
    const int lb  = (bx & 7) * 64 + (bx >> 3);  // XCD swizzle (G=512)
    const int m0  = lb * 64;
    const int ty3 = blockIdx.y;                 // tensor triple: channels [ty3*192, +192)

    // ---- stage x strip [64][192] bf16 into LDS, swizzled ----
#pragma unroll
    for (int i = 0; i < 6; ++i) {
        int il = i * 256 + tid;                 // 16B chunk id, 0..1535
        int p  = il / 24;                       // pixel row in strip
        int cc = il % 24;                       // 16B chunk within row
        uint4 v = *(const uint4*)(xb + (size_t)(m0 + p) * kC + cc * 8);
        int dst = p * 384 + ((cc * 16) ^ ((p & 7) << 4));
        *(uint4*)((char*)xs + dst) = v;
    }
    __syncthreads();

    const int lane = tid & 63;
    const int wave = tid >> 6;
    const int l15  = lane & 15;
    const int q    = lane >> 4;
    const int sbase = ty3 * 12 + wave * 3;      // first of 3 N-strips for this wave

    f4v acc[3][4];
#pragma unroll
    for (int i = 0; i < 3; ++i)
#pragma unroll
        for (int m = 0; m < 4; ++m) acc[i][m] = (f4v){0.f, 0.f, 0.f, 0.f};

    const ushort_t* ap = awb + ((size_t)sbase * 6 * 64 + lane) * 8;

#pragma unroll
    for (int kc = 0; kc < 6; ++kc) {
        s8v bfr[4];
#pragma unroll
        for (int m = 0; m < 4; ++m) {
            int row = m * 16 + l15;
            int col = (kc * 64 + q * 16) ^ ((l15 & 7) << 4);
            bfr[m] = *(const s8v*)((const char*)xs + row * 384 + col);
        }
#pragma unroll
        for (int i = 0; i < 3; ++i) {
            s8v a = *(const s8v*)(ap + (size_t)(i * 6 + kc) * 64 * 8);
#pragma unroll
            for (int m = 0; m < 4; ++m)
                acc[i][m] = __builtin_amdgcn_mfma_f32_16x16x32_bf16(a, bfr[m], acc[i][m], 0, 0, 0);
        }
    }

    // ---- store: D col (l15) = pixel, row (q*4+reg) = channel-in-strip ----
#pragma unroll
    for (int i = 0; i < 3; ++i) {
        int s   = sbase + i;
        int ty  = s >> 2;                       // tensor 0..8
        int c64 = (s & 3) * 16 + q * 4;         // channel within tensor
        ushort_t* obase = qkvpx + (size_t)ty * kM * 64 + (size_t)m0 * 64 + c64;
#pragma unroll
        for (int m = 0; m < 4; ++m) {
            f4v v = acc[i][m];
            uint2 u;
            u.x = (unsigned)bf16r(v.x) | ((unsigned)bf16r(v.y) << 16);
            u.y = (unsigned)bf16r(v.z) | ((unsigned)bf16r(v.w) << 16);
            *(uint2*)(obase + (size_t)(m * 16 + l15) * 64) = u;
        }
    }
}

// ---------------------------------------------------------------------------
// Kernel 2: offsets conv via bf16 MFMA over pixel-major k.
// ---------------------------------------------------------------------------
__global__ __launch_bounds__(256) void off_conv_mfma(const ushort_t* __restrict__ kpx,
                                                     const ushort_t* __restrict__ owtb,
                                                     const float* __restrict__ obias,
                                                     float* __restrict__ offb,
                                                     int dil) {
    const int lb = (blockIdx.x & 7) * 64 + (blockIdx.x >> 3);   // XCD swizzle (G=512)
    const int b = lb >> 6;
    const int y = lb & 63;
    const int tid  = threadIdx.x;
    const int lane = tid & 63;
    const int wave = tid >> 6;
    const int l15  = lane & 15;
    const int q    = lane >> 4;
    const int px   = wave * 16 + l15;

    const ushort_t* inpx = kpx + (size_t)b * kHW * 64 + q * 8;

    f4v acc[2];
    acc[0] = (f4v){0.f, 0.f, 0.f, 0.f};
    acc[1] = (f4v){0.f, 0.f, 0.f, 0.f};

#pragma unroll
    for (int kk = 0; kk < 9; ++kk) {
        const int yy = y + (kk / 3 - 1) * dil;
        const int xx = px + (kk % 3 - 1) * dil;
        const bool valid = (yy >= 0) & (yy < kH) & (xx >= 0) & (xx < kW);
        const size_t idx = valid ? (size_t)(yy * kW + xx) * 64 : 0;
        s8v a0 = *(const s8v*)(inpx + idx);
        s8v a1 = *(const s8v*)(inpx + idx + 32);
        if (!valid) {
            a0 = (s8v){0, 0, 0, 0, 0, 0, 0, 0};
            a1 = (s8v){0, 0, 0, 0, 0, 0, 0, 0};
        }
        const ushort_t* wb = owtb + (size_t)kk * 2048 + l15 * 64 + q * 8;
#pragma unroll
        for (int nbk = 0; nbk < 2; ++nbk) {
            s8v b0 = *(const s8v*)(wb + nbk * 1024);
            s8v b1 = *(const s8v*)(wb + nbk * 1024 + 32);
            acc[nbk] = __builtin_amdgcn_mfma_f32_16x16x32_bf16(a0, b0, acc[nbk], 0, 0, 0);
            acc[nbk] = __builtin_amdgcn_mfma_f32_16x16x32_bf16(a1, b1, acc[nbk], 0, 0, 0);
        }
    }
#pragma unroll
    for (int nbk = 0; nbk < 2; ++nbk) {
        int n = nbk * 16 + l15;
        if (n < 18) {
            float bias = obias[n];
            f4v v = acc[nbk];
            v.x += bias; v.y += bias; v.z += bias; v.w += bias;
            *(f4v*)&offb[((size_t)b * 18 + n) * kHW + y * kW + wave * 16 + q * 4] = v;
        }
    }
}

// ---------------------------------------------------------------------------
// Kernel 3: deformable 3x3 conv via bf16 MFMA, pixel-major in AND out.
// ---------------------------------------------------------------------------
__global__ __launch_bounds__(256) void deform_mfma(const ushort_t* __restrict__ kpx,
                                                   const ushort_t* __restrict__ vpx,
                                                   const float* __restrict__ offb,
                                                   const ushort_t* __restrict__ dwtb,
                                                   const float* __restrict__ db,
                                                   ushort_t* __restrict__ outkpx,
                                                   ushort_t* __restrict__ outvpx,
                                                   int dil) {
    const int lb = (blockIdx.x & 7) * 128 + (blockIdx.x >> 3);  // XCD swizzle (G=1024)
    const int t = lb >> 9;          // 0 = k, 1 = v
    const int b = (lb >> 6) & 7;
    const int y = lb & 63;
    const int tid  = threadIdx.x;
    const int lane = tid & 63;
    const int wave = tid >> 6;
    const int l15  = lane & 15;
    const int q    = lane >> 4;
    const int px   = wave * 16 + l15;   // B-operand pixel for this lane

    const ushort_t* inpx = (t ? vpx : kpx) + (size_t)b * kHW * 64 + q * 8;
    ushort_t* outp = t ? outvpx : outkpx;

    f4v acc[4];
#pragma unroll
    for (int ob = 0; ob < 4; ++ob) acc[ob] = (f4v){0.f, 0.f, 0.f, 0.f};

    // prefetch all 18 offset channels for my pixel
    const float* offrow = offb + (size_t)b * 18 * kHW + y * kW + px;
    float offv[18];
#pragma unroll
    for (int i = 0; i < 18; ++i) offv[i] = offrow[(size_t)i * kHW];

    auto sample_tap = [&](int kk, s8v* c, float* w) {
        float oy = offv[kk * 2 + 0];
        float ox = offv[kk * 2 + 1];
        float py  = (float)y  + (float)((kk / 3 - 1) * dil) + oy;
        float pxf = (float)px + (float)((kk % 3 - 1) * dil) + ox;
        float fy = floorf(py), fx = floorf(pxf);
        float wy = py - fy, wx = pxf - fx;
        int y0 = (int)fy, x0 = (int)fx;
        int y1 = y0 + 1, x1 = x0 + 1;
        int y0c = min(max(y0, 0), kH - 1), x0c = min(max(x0, 0), kW - 1);
        int y1c = min(max(y1, 0), kH - 1), x1c = min(max(x1, 0), kW - 1);
        bool vy0 = (y0 >= 0) & (y0 < kH), vx0 = (x0 >= 0) & (x0 < kW);
        bool vy1 = (y1 >= 0) & (y1 < kH), vx1 = (x1 >= 0) & (x1 < kW);
        size_t i00 = (size_t)(y0c * kW + x0c) * 64;
        size_t i01 = (size_t)(y0c * kW + x1c) * 64;
        size_t i10 = (size_t)(y1c * kW + x0c) * 64;
        size_t i11 = (size_t)(y1c * kW + x1c) * 64;
        w[0] = (vy0 && vx0) ? (1.f - wy) * (1.f - wx) : 0.f;
        w[1] = (vy0 && vx1) ? (1.f - wy) * wx : 0.f;
        w[2] = (vy1 && vx0) ? wy * (1.f - wx) : 0.f;
        w[3] = (vy1 && vx1) ? wy * wx : 0.f;
        c[0] = *(const s8v*)(inpx + i00);
        c[1] = *(const s8v*)(inpx + i00 + 32);
        c[2] = *(const s8v*)(inpx + i01);
        c[3] = *(const s8v*)(inpx + i01 + 32);
        c[4] = *(const s8v*)(inpx + i10);
        c[5] = *(const s8v*)(inpx + i10 + 32);
        c[6] = *(const s8v*)(inpx + i11);
        c[7] = *(const s8v*)(inpx + i11 + 32);
    };

    s8v cur[8], nxt[8];
    float wcur[4], wnxt[4];
    sample_tap(0, cur, wcur);
#pragma unroll
    for (int kk = 0; kk < 9; ++kk) {
        if (kk < 8) sample_tap(kk + 1, nxt, wnxt);   // prefetch next tap
        // bilinear for current tap -> two B-frags (channel chunks)
        s8v b0, b1;
#pragma unroll
        for (int j = 0; j < 8; ++j) {
            float v0 = wcur[0] * bfu(cur[0][j]) + wcur[1] * bfu(cur[2][j]) +
                       wcur[2] * bfu(cur[4][j]) + wcur[3] * bfu(cur[6][j]);
            float v1 = wcur[0] * bfu(cur[1][j]) + wcur[1] * bfu(cur[3][j]) +
                       wcur[2] * bfu(cur[5][j]) + wcur[3] * bfu(cur[7][j]);
            b0[j] = (short)bf16r(v0);
            b1[j] = (short)bf16r(v1);
        }
        // A-frags: dwtb[kk][o = obb*16+l15][c = q*8 (+32)]
        const ushort_t* wb = dwtb + (size_t)kk * 4096 + l15 * 64 + q * 8;
#pragma unroll
        for (int obb = 0; obb < 4; ++obb) {
            s8v a0w = *(const s8v*)(wb + obb * 1024);
            s8v a1w = *(const s8v*)(wb + obb * 1024 + 32);
            acc[obb] = __builtin_amdgcn_mfma_f32_16x16x32_bf16(a0w, b0, acc[obb], 0, 0, 0);
            acc[obb] = __builtin_amdgcn_mfma_f32_16x16x32_bf16(a1w, b1, acc[obb], 0, 0, 0);
        }
        if (kk < 8) {
#pragma unroll
            for (int i = 0; i < 8; ++i) cur[i] = nxt[i];
#pragma unroll
            for (int i = 0; i < 4; ++i) wcur[i] = wnxt[i];
        }
    }
    // store: lane holds o = obb*16 + q*4 + reg at pixel px -> bf16 pixel-major
    ushort_t* orow = outp + ((size_t)b * kHW + y * kW + px) * 64 + q * 4;
#pragma unroll
    for (int obb = 0; obb < 4; ++obb) {
        float4 bias = *(const float4*)&db[obb * 16 + q * 4];
        f4v v = acc[obb];
        uint2 u;
        u.x = (unsigned)bf16r(v.x + bias.x) | ((unsigned)bf16r(v.y + bias.y) << 16);
        u.y = (unsigned)bf16r(v.z + bias.z) | ((unsigned)bf16r(v.w + bias.w) << 16);
        *(uint2*)(orow + obb * 16) = u;
    }
}

// ---------------------------------------------------------------------------
// Kernel 4: 9-tap local attention on bf16 PIXEL-MAJOR q/k/v.
// Block = 1 row: 256 threads = 64 px x 4 channel-groups (16 ch each).
// ---------------------------------------------------------------------------
__global__ __launch_bounds__(256) void attn_px(const ushort_t* __restrict__ qpx,
                                               const ushort_t* __restrict__ kpx,
                                               const ushort_t* __restrict__ vpx,
                                               ushort_t* __restrict__ aopx,
                                               int branch, int dil) {
    const int lb = (blockIdx.x & 7) * 64 + (blockIdx.x >> 3);   // XCD swizzle (G=512)
    const int b = lb >> 6;
    const int y = lb & 63;
    const int tid  = threadIdx.x;
    const int wave = tid >> 6;
    const int l    = tid & 63;
    const int pxq  = l >> 2;
    const int cg   = l & 3;
    const int x = wave * 16 + pxq;
    const int p = y * kW + x;
    const size_t pbase = (size_t)b * kHW;

    const ushort_t* qb = qpx + (pbase + p) * 64 + cg * 16;
    s8v q0 = *(const s8v*)qb;
    s8v q1 = *(const s8v*)(qb + 8);
    float qf[16];
#pragma unroll
    for (int j = 0; j < 8; ++j) { qf[j] = bfu(q0[j]); qf[8 + j] = bfu(q1[j]); }

    int offs[9]; float msk[9];
#pragma unroll
    for (int kk = 0; kk < 9; ++kk) {
        int dy = (kk / 3 - 1) * dil, dx = (kk % 3 - 1) * dil;
        int yy = y + dy, xx = x + dx;
        bool v = (yy >= 0) & (yy < kH) & (xx >= 0) & (xx < kW);
        offs[kk] = v ? (p + dy * kW + dx) : p;
        msk[kk] = v ? 1.f : 0.f;
    }
    float e[9];
#pragma unroll
    for (int kk = 0; kk < 9; ++kk) {
        const ushort_t* kp = kpx + (pbase + offs[kk]) * 64 + cg * 16;
        s8v k0 = *(const s8v*)kp;
        s8v k1 = *(const s8v*)(kp + 8);
        float s = 0.f;
#pragma unroll
        for (int j = 0; j < 8; ++j) {
            s += qf[j] * bfu(k0[j]);
            s += qf[8 + j] * bfu(k1[j]);
        }
        s += __shfl_xor(s, 1);
        s += __shfl_xor(s, 2);
        e[kk] = s * 0.125f * msk[kk];
    }
    float mx = -1e30f;
#pragma unroll
    for (int kk = 0; kk < 9; ++kk) mx = fmaxf(mx, e[kk]);
    float ssum = 0.f;
#pragma unroll
    for (int kk = 0; kk < 9; ++kk) { e[kk] = __expf(e[kk] - mx); ssum += e[kk]; }
    float inv = 1.f / ssum;
#pragma unroll
    for (int kk = 0; kk < 9; ++kk) e[kk] = e[kk] * inv * msk[kk];

    float acc[16];
#pragma unroll
    for (int j = 0; j < 16; ++j) acc[j] = 0.f;
#pragma unroll
    for (int kk = 0; kk < 9; ++kk) {
        const ushort_t* vp = vpx + (pbase + offs[kk]) * 64 + cg * 16;
        s8v v0 = *(const s8v*)vp;
        s8v v1 = *(const s8v*)(vp + 8);
        float w = e[kk];
#pragma unroll
        for (int j = 0; j < 8; ++j) {
            acc[j] += w * bfu(v0[j]);
            acc[8 + j] += w * bfu(v1[j]);
        }
    }
    unsigned u[8];
#pragma unroll
    for (int i = 0; i < 8; ++i)
        u[i] = (unsigned)bf16r(acc[2 * i]) | ((unsigned)bf16r(acc[2 * i + 1]) << 16);
    ushort_t* ob = aopx + (pbase + p) * kC + branch * 64 + cg * 16;
    *(uint4*)ob = make_uint4(u[0], u[1], u[2], u[3]);
    *(uint4*)(ob + 8) = make_uint4(u[4], u[5], u[6], u[7]);
}

// ---------------------------------------------------------------------------
// Kernel 5: output projection via bf16 MFMA on pixel-major ao.
// ---------------------------------------------------------------------------
__global__ __launch_bounds__(256) void proj_mfma(const ushort_t* __restrict__ aopx,
                                                 const ushort_t* __restrict__ pwb,
                                                 const float* __restrict__ pb,
                                                 float* __restrict__ out) {
    const int tid  = threadIdx.x;
    const int lane = tid & 63;
    const int wave = tid >> 6;
    const int l15  = lane & 15;
    const int q    = lane >> 4;
    const int m0   = blockIdx.x * 64;
    const int nb   = blockIdx.y * 64 + wave * 16;

    f4v acc[4];
#pragma unroll
    for (int ob = 0; ob < 4; ++ob) acc[ob] = (f4v){0.f, 0.f, 0.f, 0.f};

    const ushort_t* aw = pwb + (size_t)(nb + l15) * kC + q * 8;
    const ushort_t* bx = aopx + (size_t)(m0 + l15) * kC + q * 8;
#pragma unroll
    for (int kc = 0; kc < 6; ++kc) {
        s8v a = *(const s8v*)(aw + kc * 32);
#pragma unroll
        for (int ob = 0; ob < 4; ++ob) {
            s8v b = *(const s8v*)(bx + (size_t)(ob * 16) * kC + kc * 32);
            acc[ob] = __builtin_amdgcn_mfma_f32_16x16x32_bf16(a, b, acc[ob], 0, 0, 0);
        }
    }
    float4 bias = *(const float4*)&pb[nb + q * 4];
#pragma unroll
    for (int ob = 0; ob < 4; ++ob) {
        int m = m0 + ob * 16 + l15;
        f4v v = acc[ob];
        v.x += bias.x; v.y += bias.y; v.z += bias.z; v.w += bias.w;
        *(f4v*)&out[(size_t)m * kC + nb + q * 4] = v;
    }
}

// ---------------------------------------------------------------------------
// Host launcher.  Workspace (~63 MB, well under the proven 120 MB):
//   fp32: offb 18 planes
//   bf16: xb (M*192) | qkvpx (9*M*64) | kdpx, vdpx (M*64) | aopx (M*192) |
//         awb (packed qkv W) | pwb | dwtb2/3 | owtb2/3
// ---------------------------------------------------------------------------
extern "C" void kernel_launch(void* const* d_in, const int* in_sizes, int n_in,
                              void* d_out, int out_size, void* d_ws, size_t ws_size,
                              hipStream_t stream) {
    const float* x      = (const float*)d_in[0];
    const float* qkv_w  = (const float*)d_in[1];
    const float* proj_w = (const float*)d_in[2];
    const float* proj_b = (const float*)d_in[3];
    const float* off_w2 = (const float*)d_in[4];
    const float* off_b2 = (const float*)d_in[5];
    const float* def_w2 = (const float*)d_in[6];
    const float* def_b2 = (const float*)d_in[7];
    const float* off_w3 = (const float*)d_in[8];
    const float* off_b3 = (const float*)d_in[9];
    const float* def_w3 = (const float*)d_in[10];
    const float* def_b3 = (const float*)d_in[11];
    float* out = (float*)d_out;

    float* ws   = (float*)d_ws;
    float* offb = ws;                               // 18 * M
    ushort_t* us = (ushort_t*)(offb + (size_t)18 * kM);
    ushort_t* xb     = us;  us += (size_t)kM * kC;
    ushort_t* qkvpx  = us;  us += (size_t)9 * kM * 64;
    ushort_t* kdpx   = us;  us += (size_t)kM * 64;
    ushort_t* vdpx   = us;  us += (size_t)kM * 64;
    ushort_t* aopx   = us;  us += (size_t)kM * kC;
    ushort_t* awb    = us;  us += (size_t)kNQKV * kC;   // 36*6*64*8 == 576*192
    ushort_t* pwb    = us;  us += (size_t)kC * kC;
    ushort_t* dwtb2  = us;  us += kD * kD * 9;
    ushort_t* dwtb3  = us;  us += kD * kD * 9;
    ushort_t* owtb2  = us;  us += 9 * 32 * 64;
    ushort_t* owtb3  = us;  us += 9 * 32 * 64;

    // 0. bf16 conversions and weight transposes/packs
    cvt_bf16<<<(kM * kC / 2 + 255) / 256, 256, 0, stream>>>(x, (unsigned*)xb, kM * kC / 2);
    qw_pack<<<54, 256, 0, stream>>>(qkv_w, awb);
    cvt_bf16<<<(kC * kC / 2 + 255) / 256, 256, 0, stream>>>(proj_w, (unsigned*)pwb, kC * kC / 2);
    dw_tb<<<144, 256, 0, stream>>>(def_w2, dwtb2);
    dw_tb<<<144, 256, 0, stream>>>(def_w3, dwtb3);
    ow_tb<<<72, 256, 0, stream>>>(off_w2, owtb2);
    ow_tb<<<72, 256, 0, stream>>>(off_w3, owtb3);

    // per-tensor pixel-major slices
    ushort_t* q0 = qkvpx;
    ushort_t* q1 = qkvpx + (size_t)1 * kM * 64;
    ushort_t* q2 = qkvpx + (size_t)2 * kM * 64;
    ushort_t* k0 = qkvpx + (size_t)3 * kM * 64;
    ushort_t* k1 = qkvpx + (size_t)4 * kM * 64;
    ushort_t* k2 = qkvpx + (size_t)5 * kM * 64;
    ushort_t* v0 = qkvpx + (size_t)6 * kM * 64;
    ushort_t* v1 = qkvpx + (size_t)7 * kM * 64;
    ushort_t* v2 = qkvpx + (size_t)8 * kM * 64;

    // 1. QKV projection -> 9 bf16 pixel-major tensors (LDS-staged GEMM)
    qkv_mfma3<<<dim3(kM / 64, 3), 256, 0, stream>>>(xb, awb, qkvpx);

    // 2. branch 0 (dil=1)
    attn_px<<<kB * kH, 256, 0, stream>>>(q0, k0, v0, aopx, 0, 1);

    // 3. branch 1 (dil=2)
    off_conv_mfma<<<512, 256, 0, stream>>>(k1, owtb2, off_b2, offb, 2);
    deform_mfma<<<1024, 256, 0, stream>>>(k1, v1, offb, dwtb2, def_b2, kdpx, vdpx, 2);
    attn_px<<<kB * kH, 256, 0, stream>>>(q1, kdpx, vdpx, aopx, 1, 2);

    // 4. branch 2 (dil=3)
    off_conv_mfma<<<512, 256, 0, stream>>>(k2, owtb3, off_b3, offb, 3);
    deform_mfma<<<1024, 256, 0, stream>>>(k2, v2, offb, dwtb3, def_b3, kdpx, vdpx, 3);
    attn_px<<<kB * kH, 256, 0, stream>>>(q2, kdpx, vdpx, aopx, 2, 3);

    // 5. output projection (bf16 MFMA, fp32 out)
    proj_mfma<<<dim3(kM / 64, 3), 256, 0, stream>>>(aopx, pwb, proj_b, out);
}